// Round 3
// baseline (830.444 us; speedup 1.0000x reference)
//
#include <hip/hip_runtime.h>
#include <stdint.h>
#include <math.h>

#define AN 10000            // N nodes
#define NPAD 10048          // k-stride for transposed bf16 Y arrays
#define KZ 16               // contiguous k-split across blockIdx.y
#define NTILES 157          // ceil(10000/64)
#define TPB 10              // tiles per block = ceil(157/16)

using short8 = __attribute__((ext_vector_type(8))) short;
using f32x4  = __attribute__((ext_vector_type(4))) float;

__device__ __forceinline__ uint32_t fbits(float x){ union{float f;uint32_t u;} v; v.f=x; return v.u; }
__device__ __forceinline__ float    fval(uint32_t u){ union{float f;uint32_t u;} v; v.u=u; return v.f; }

// split a into bf16 hi (truncate) + bf16 lo (truncate of remainder)
__device__ __forceinline__ void split1(float a, uint16_t& h, uint16_t& l){
  uint32_t ua = fbits(a);
  float lo = a - fval(ua & 0xFFFF0000u);
  h = (uint16_t)(ua >> 16);
  l = (uint16_t)(fbits(lo) >> 16);
}

// 8 floats -> hi/lo bf16 fragments
__device__ __forceinline__ void split8(const float4& a, const float4& b, short8& h, short8& l){
  float v[8] = {a.x, a.y, a.z, a.w, b.x, b.y, b.z, b.w};
  #pragma unroll
  for (int i = 0; i < 8; ++i) {
    uint32_t u = fbits(v[i]);
    h[i] = (short)(u >> 16);
    float r = v[i] - fval(u & 0xFFFF0000u);
    l[i] = (short)(fbits(r) >> 16);
  }
}

// ---------------- K1: Y1 = [T@Ws1 | (T|P)@Wma] -> transposed bf16 hi/lo;
//                     Z2 = T@Ws2+bs (fp32), Zm = (T|P)@Wmb+bm (fp32)
__global__ __launch_bounds__(256) void k1(
    const float* __restrict__ T, const float* __restrict__ P,
    const float* __restrict__ Ws1, const float* __restrict__ Ws2,
    const float* __restrict__ bs, const float* __restrict__ Wma,
    const float* __restrict__ Wmb, const float* __restrict__ bm,
    uint16_t* __restrict__ Yth, uint16_t* __restrict__ Ytl,
    float* __restrict__ Z2, float* __restrict__ Zm) {
  __shared__ float Xl[16 * 192];               // 16 rows x (128 T | 64 P)
  __shared__ float RedY[16 * 7], RedZ[16 * 7];
  int t = threadIdx.x;
  int r0 = blockIdx.x * 16;                    // 625 blocks * 16 = 10000
  for (int s = t; s < 768; s += 256) {
    int r = s / 48, c4 = (s % 48) * 4;
    const float* src = (c4 < 128) ? &T[(size_t)(r0 + r) * 128 + c4]
                                  : &P[(size_t)(r0 + r) * 64 + (c4 - 128)];
    *(float4*)&Xl[r * 192 + c4] = *(const float4*)src;
  }
  __syncthreads();
  // part A: 32 sec cols x 16 rows (2 rows per thread)
  {
    int c = t & 31, r = t >> 5;
    float y0 = 0, z0 = 0, y1 = 0, z1 = 0;
    const float* x0 = &Xl[r * 192];
    const float* x1 = &Xl[(r + 8) * 192];
    #pragma unroll 8
    for (int k = 0; k < 128; ++k) {
      float w1 = Ws1[k * 32 + c], w2 = Ws2[k * 32 + c];
      float a0 = x0[k], a1 = x1[k];
      y0 += a0 * w1; z0 += a0 * w2;
      y1 += a1 * w1; z1 += a1 * w2;
    }
    int rowA = r0 + r, rowB = r0 + r + 8;
    float bsv = bs[c];
    Z2[rowA * 32 + c] = z0 + bsv;
    Z2[rowB * 32 + c] = z1 + bsv;
    uint16_t h, l;
    split1(y0, h, l); Yth[c * NPAD + rowA] = h; Ytl[c * NPAD + rowA] = l;
    split1(y1, h, l); Yth[c * NPAD + rowB] = h; Ytl[c * NPAD + rowB] = l;
  }
  // part B: 7 main cols x 16 rows, k split in halves across lane pairs
  int u = t & 15, r = t >> 4;
  int j = u % 7, half = u / 7;
  float ym = 0, zm = 0;
  if (u < 14) {
    int kb = half * 96;
    const float* xr = &Xl[r * 192];
    #pragma unroll 4
    for (int i = 0; i < 96; ++i) {
      int k = kb + i;
      ym += xr[k] * Wma[k * 7 + j];
      zm += xr[k] * Wmb[k * 7 + j];
    }
    if (half == 1) { RedY[r * 7 + j] = ym; RedZ[r * 7 + j] = zm; }
  }
  __syncthreads();
  if (u < 7) {
    ym += RedY[r * 7 + j]; zm += RedZ[r * 7 + j];
    int row = r0 + r;
    uint16_t h, l;
    split1(ym, h, l);
    Yth[(32 + j) * NPAD + row] = h; Ytl[(32 + j) * NPAD + row] = l;
    Zm[row * 7 + j] = zm + bm[j];
  }
}

// ---------------- A-streaming MFMA kernel, barrier-free, LDS-free.
// Block 256 = 4 waves; wave w -> output rows r0+16w..+15.
// Lane (m,q): A-frag rows r0+16w+m, k = kt+ks*32+q*8..+7 direct from global.
// B-frag: Yt[col 16f+m][same k] direct from global (bf16, L1/L2-resident).
// Contiguous k-split over blockIdx.y, partial sums to Spart[kz] (no atomics).
template<int NCF, int NC, int CST>
__global__ __launch_bounds__(256) void k_spmm(
    const float* __restrict__ A, const uint16_t* __restrict__ Yth,
    const uint16_t* __restrict__ Ytl, float* __restrict__ Spart) {
  int t = threadIdx.x;
  int w = t >> 6, lane = t & 63;
  int m = lane & 15, q = lane >> 4;
  int r0 = blockIdx.x * 64;
  int kz = blockIdx.y;
  int row = r0 + 16 * w + m;
  int rowc = row < AN ? row : AN - 1;
  const float* arow = A + (size_t)rowc * AN;
  const uint16_t* yhp[NCF];
  const uint16_t* ylp[NCF];
  #pragma unroll
  for (int f = 0; f < NCF; ++f) {
    int col = 16 * f + m; if (col > NC - 1) col = NC - 1;
    yhp[f] = Yth + (size_t)col * NPAD;
    ylp[f] = Ytl + (size_t)col * NPAD;
  }
  f32x4 acc[NCF];
  #pragma unroll
  for (int f = 0; f < NCF; ++f) acc[f] = (f32x4){0.f, 0.f, 0.f, 0.f};

  int t0 = kz * TPB;
  int t1 = t0 + TPB; if (t1 > NTILES) t1 = NTILES;
  int te = t1 < NTILES - 1 ? t1 : NTILES - 1;   // fast tiles [t0, te)
  int kq = q * 8;

  for (int tile = t0; tile < te; ++tile) {
    int kt = tile * 64;
    #pragma unroll
    for (int ks = 0; ks < 2; ++ks) {
      int k = kt + ks * 32 + kq;
      float4 a0 = *(const float4*)(arow + k);
      float4 a1 = *(const float4*)(arow + k + 4);
      short8 ah, al;
      split8(a0, a1, ah, al);
      #pragma unroll
      for (int f = 0; f < NCF; ++f) {
        short8 vyh = *(const short8*)(yhp[f] + k);
        short8 vyl = *(const short8*)(ylp[f] + k);
        acc[f] = __builtin_amdgcn_mfma_f32_16x16x32_bf16(ah, vyh, acc[f], 0, 0, 0);
        acc[f] = __builtin_amdgcn_mfma_f32_16x16x32_bf16(ah, vyl, acc[f], 0, 0, 0);
        acc[f] = __builtin_amdgcn_mfma_f32_16x16x32_bf16(al, vyh, acc[f], 0, 0, 0);
      }
    }
  }
  if (t1 == NTILES) {                           // guarded tile 156 (k 9984..9999)
    int kt = (NTILES - 1) * 64;
    #pragma unroll
    for (int ks = 0; ks < 2; ++ks) {
      int k = kt + ks * 32 + kq;
      float4 a0 = make_float4(0.f, 0.f, 0.f, 0.f);
      float4 a1 = make_float4(0.f, 0.f, 0.f, 0.f);
      if (k + 8 <= AN) {
        a0 = *(const float4*)(arow + k);
        a1 = *(const float4*)(arow + k + 4);
      }
      short8 ah, al;
      split8(a0, a1, ah, al);
      #pragma unroll
      for (int f = 0; f < NCF; ++f) {
        short8 vyh = *(const short8*)(yhp[f] + k);   // within NPAD alloc; A=0 kills garbage
        short8 vyl = *(const short8*)(ylp[f] + k);
        acc[f] = __builtin_amdgcn_mfma_f32_16x16x32_bf16(ah, vyh, acc[f], 0, 0, 0);
        acc[f] = __builtin_amdgcn_mfma_f32_16x16x32_bf16(ah, vyl, acc[f], 0, 0, 0);
        acc[f] = __builtin_amdgcn_mfma_f32_16x16x32_bf16(al, vyh, acc[f], 0, 0, 0);
      }
    }
  }
  // C/D layout: col = 16f + m, row = r0 + 16w + q*4 + reg
  float* outp = Spart + (size_t)kz * AN * CST;
  int rb = r0 + 16 * w + q * 4;
  #pragma unroll
  for (int f = 0; f < NCF; ++f) {
    int col = 16 * f + m;
    if (col < NC) {
      #pragma unroll
      for (int r4 = 0; r4 < 4; ++r4) {
        int rr = rb + r4;
        if (rr < AN) outp[(size_t)rr * CST + col] = acc[f][r4];
      }
    }
  }
}

// ---------------- K2b: reduce 16 partials; sec = relu(S1+Z2), M0 = 0.5*v2*(Sm+Zm)
__global__ __launch_bounds__(256) void k2b(
    const float* __restrict__ Spart, const float* __restrict__ Z2,
    const float* __restrict__ Zm, const float* __restrict__ v2p,
    float* __restrict__ sec, float* __restrict__ M0) {
  int g = blockIdx.x * 256 + threadIdx.x;
  if (g >= AN * 40) return;
  int row = g / 40, c = g - row * 40;
  if (c >= 39) return;
  float s = 0.f;
  #pragma unroll
  for (int kz = 0; kz < KZ; ++kz) s += Spart[(size_t)kz * AN * 40 + g];
  if (c < 32) {
    sec[row * 32 + c] = fmaxf(s + Z2[row * 32 + c], 0.f);
  } else {
    int j = c - 32;
    M0[row * 7 + j] = 0.5f * v2p[0] * (s + Zm[row * 7 + j]);
  }
}

// ---------------- K2c: Y2 = [sec|P]@Wm2a -> transposed bf16 hi/lo;
//                      C0 = M0 + 0.5*v1*([sec|P]@Wm2b + bm2)
__global__ __launch_bounds__(256) void k2c(
    const float* __restrict__ sec, const float* __restrict__ P,
    const float* __restrict__ Wm2a, const float* __restrict__ Wm2b,
    const float* __restrict__ bm2, const float* __restrict__ v1p,
    const float* __restrict__ M0,
    uint16_t* __restrict__ Y2th, uint16_t* __restrict__ Y2tl,
    float* __restrict__ C0) {
  __shared__ float Xc[16 * 96];
  __shared__ float RedY[16 * 7], RedZ[16 * 7];
  int t = threadIdx.x;
  int r0 = blockIdx.x * 16;
  for (int s = t; s < 384; s += 256) {
    int r = s / 24, c4 = (s % 24) * 4;
    const float* src = (c4 < 32) ? &sec[(size_t)(r0 + r) * 32 + c4]
                                 : &P[(size_t)(r0 + r) * 64 + (c4 - 32)];
    *(float4*)&Xc[r * 96 + c4] = *(const float4*)src;
  }
  __syncthreads();
  int u = t & 15, r = t >> 4;
  int j = u % 7, half = u / 7;
  float y = 0, z = 0;
  if (u < 14) {
    int kb = half * 48;
    const float* xr = &Xc[r * 96];
    #pragma unroll 4
    for (int i = 0; i < 48; ++i) {
      int k = kb + i;
      y += xr[k] * Wm2a[k * 7 + j];
      z += xr[k] * Wm2b[k * 7 + j];
    }
    if (half == 1) { RedY[r * 7 + j] = y; RedZ[r * 7 + j] = z; }
  }
  __syncthreads();
  if (u < 7) {
    y += RedY[r * 7 + j]; z += RedZ[r * 7 + j];
    int row = r0 + r;
    uint16_t h, l;
    split1(y, h, l);
    Y2th[j * NPAD + row] = h; Y2tl[j * NPAD + row] = l;
    C0[row * 7 + j] = M0[row * 7 + j] + 0.5f * v1p[0] * (z + bm2[j]);
  }
}

// ---------------- K3b: reduce 16 partials; combined = C0 + 0.5*v1*S2 ; softmax(7)
__global__ __launch_bounds__(256) void k3b(
    const float* __restrict__ S2part, const float* __restrict__ C0,
    const float* __restrict__ v1p, float* __restrict__ out) {
  int row = blockIdx.x * 256 + threadIdx.x;
  if (row >= AN) return;
  float s[8];
  #pragma unroll
  for (int j = 0; j < 8; ++j) s[j] = 0.f;
  for (int kz = 0; kz < KZ; ++kz) {
    const float* p = &S2part[(size_t)kz * AN * 8 + (size_t)row * 8];
    float4 u0 = *(const float4*)p;
    float4 u1 = *(const float4*)(p + 4);
    s[0] += u0.x; s[1] += u0.y; s[2] += u0.z; s[3] += u0.w;
    s[4] += u1.x; s[5] += u1.y; s[6] += u1.z;
  }
  float v1h = 0.5f * v1p[0];
  float comb[7];
  float mx = -1e30f;
  #pragma unroll
  for (int j = 0; j < 7; ++j) {
    float cv = C0[row * 7 + j] + v1h * s[j];
    comb[j] = cv; mx = fmaxf(mx, cv);
  }
  float sum = 0.f;
  #pragma unroll
  for (int j = 0; j < 7; ++j) { comb[j] = expf(comb[j] - mx); sum += comb[j]; }
  float inv = 1.f / sum;
  #pragma unroll
  for (int j = 0; j < 7; ++j) out[row * 7 + j] = comb[j] * inv;
}

extern "C" void kernel_launch(void* const* d_in, const int* in_sizes, int n_in,
                              void* d_out, int out_size, void* d_ws, size_t ws_size,
                              hipStream_t stream) {
  const float* T    = (const float*)d_in[0];
  const float* A    = (const float*)d_in[1];
  const float* P    = (const float*)d_in[2];
  const float* Ws1  = (const float*)d_in[3];
  const float* Ws2  = (const float*)d_in[4];
  const float* bs   = (const float*)d_in[5];
  const float* Wm2a = (const float*)d_in[6];
  const float* Wm2b = (const float*)d_in[7];
  const float* bm2  = (const float*)d_in[8];
  const float* Wma  = (const float*)d_in[9];
  const float* Wmb  = (const float*)d_in[10];
  const float* bm   = (const float*)d_in[11];
  const float* v1   = (const float*)d_in[12];
  const float* v2   = (const float*)d_in[13];
  float* out = (float*)d_out;

  float* ws = (float*)d_ws;
  float* Spart  = ws;                               // [16][10000][40]
  float* S2part = Spart + (size_t)KZ * AN * 40;     // [16][10000][8]
  float* Z2     = S2part + (size_t)KZ * AN * 8;     // [10000][32]
  float* Zm     = Z2 + (size_t)AN * 32;             // [10000][7]
  float* sec    = Zm + (size_t)AN * 7;              // [10000][32]
  float* M0     = sec + (size_t)AN * 32;            // [10000][7]
  float* C0     = M0 + (size_t)AN * 7;              // [10000][7]
  uint16_t* Yth  = (uint16_t*)(C0 + (size_t)AN * 7); // [40][NPAD]
  uint16_t* Ytl  = Yth + (size_t)40 * NPAD;
  uint16_t* Y2th = Ytl + (size_t)40 * NPAD;          // [8][NPAD]
  uint16_t* Y2tl = Y2th + (size_t)8 * NPAD;

  hipLaunchKernelGGL(k1, dim3(625), dim3(256), 0, stream,
                     T, P, Ws1, Ws2, bs, Wma, Wmb, bm, Yth, Ytl, Z2, Zm);
  hipLaunchKernelGGL((k_spmm<3, 39, 40>), dim3(NTILES, KZ), dim3(256), 0, stream,
                     A, Yth, Ytl, Spart);
  hipLaunchKernelGGL(k2b, dim3((AN * 40 + 255) / 256), dim3(256), 0, stream,
                     Spart, Z2, Zm, v2, sec, M0);
  hipLaunchKernelGGL(k2c, dim3(625), dim3(256), 0, stream,
                     sec, P, Wm2a, Wm2b, bm2, v1, M0, Y2th, Y2tl, C0);
  hipLaunchKernelGGL((k_spmm<1, 7, 8>), dim3(NTILES, KZ), dim3(256), 0, stream,
                     A, Y2th, Y2tl, S2part);
  hipLaunchKernelGGL(k3b, dim3((AN + 255) / 256), dim3(256), 0, stream,
                     S2part, C0, v1, out);
}